// Round 2
// baseline (93.402 us; speedup 1.0000x reference)
//
#include <hip/hip_runtime.h>
#include <math.h>

// Problem constants (from reference)
#define NB    16
#define NH    76
#define NW    76
#define NCELL (NH * NW)      // 5776
#define NITEM (NB * NCELL)   // 92416
#define NCH   32             // 19 + NC
#define NKP   9
#define NCLS  13
#define NT    50
#define NLROW 21             // 2*NK + 3
#define BLOCK 128
#define NPAIR (NITEM / 2)    // 46208 -- cells processed in adjacent pairs
#define GRID  (NPAIR / BLOCK) // 361 -- exact cover, 722 waves < 1024 SIMDs: 1 round

// 1/(exp(2)-1)
#define INV_EM1 0.15651764274966565f
#define SX 8.421052631578947f    // 640/76
#define SY 6.315789473684211f    // 480/76
// exp(2 - d*0.025) == exp2(C0 - d*C1)
#define C0 2.885390081777927f    // 2*log2(e)
#define C1 0.036067376022224085f // 0.025*log2(e)

__device__ __forceinline__ float sigmoidf_(float x) {
    return 1.0f / (1.0f + __expf(-x));
}

// R5: two adjacent cells per thread. NCELL(5776) and row width(76) are even, so
// a (2p, 2p+1) pair NEVER straddles a row or a batch boundary -> same b, same j,
// i2=i1+1, and channel loads become one aligned float2 per channel (halves VMEM
// instrs). LDS corner reads + t-loop branch overhead amortize over 2 items;
// staging runs 361x not 722x; 722 waves on 1024 SIMDs = single round (R1's 1444
// waves forced a 2-round makespan on 40% of SIMDs).
// Plus: wave-uniform y-band cull (exact, via shfl-reduced min/max of the wave's
// actual predicted-corner y's): corner with |dy|>=80 for all lanes contributes
// exactly 0 (dist >= |dy|) -> skip ~50% of (t,k) bodies before the d^2 math.
// Plus: exp2-direct form (v_fma + v_exp, no log2e mul).
__global__ __launch_bounds__(BLOCK) void loss_main(
    const float* __restrict__ out,   // (NB, 32, 76, 76)
    const float* __restrict__ dt,    // (NB, 32, 76, 76)
    const float* __restrict__ tgt,   // (NB, 1050)
    float* __restrict__ outp,        // scalar loss (fallback path only)
    float* __restrict__ partials,    // d_ws: one slot per block
    int use_ws)
{
    // A block spans <=2 batch values; stage both.
    __shared__ float2 s_g[2][NT][NKP];   // gt corners pre-scaled to pixels
    __shared__ int    s_gij[2][NT];      // (gj<<8)|gi
    __shared__ int    s_cls[2][NT];
    __shared__ int    s_nv[2];           // cumprod-validity count
    __shared__ float  swsum[BLOCK / 64];

    const int tid    = threadIdx.x;
    const int pair0  = blockIdx.x * BLOCK;
    const int cell00 = pair0 * 2;
    const int b0     = cell00 / NCELL;
    const int b1     = (cell00 + 2 * BLOCK - 1) / NCELL;   // b0 or b0+1

    // Stage 100 rows (2 b-values x 50 t), one row per thread.
    for (int u = tid; u < 2 * NT; u += BLOCK) {
        const int bsel = u / NT;
        const int t    = u - bsel * NT;
        const int bb   = bsel ? b1 : b0;
        const float* __restrict__ r = tgt + (size_t)bb * (NT * NLROW) + t * NLROW;
        #pragma unroll
        for (int k = 0; k < NKP; k++)
            s_g[bsel][t][k] = make_float2(r[1 + 2 * k] * 640.0f, r[2 + 2 * k] * 480.0f);
        const int gi = (int)(r[1] * (float)NW);
        const int gj = (int)(r[2] * (float)NH);
        s_gij[bsel][t] = (gj << 8) | gi;
        s_cls[bsel][t] = min(max((int)r[0], 0), NCLS - 1);
    }
    // nvalid per b via ballot: wave w handles bsel=w (BLOCK=128 -> exactly 2 waves).
    {
        const int wv = tid >> 6, ln = tid & 63;
        const int bb = wv ? b1 : b0;
        const float x0 = (ln < NT) ? tgt[(size_t)bb * (NT * NLROW) + ln * NLROW + 1] : 0.0f;
        const unsigned long long zmask = __ballot(x0 == 0.0f);  // lanes>=NT forced set
        if (ln == 0) s_nv[wv] = (int)__ffsll(zmask) - 1;
    }
    __syncthreads();

    const int p     = pair0 + tid;        // always < NPAIR (exact grid)
    const int c1g   = 2 * p;
    const int b     = c1g / NCELL;
    const int cell1 = c1g - b * NCELL;    // even; cell2 = cell1+1 same row/batch
    const int j     = cell1 / NW;
    const int i1    = cell1 - j * NW;
    const int bi    = (b != b0);
    const int nv    = s_nv[bi];
    const int myg1  = (j << 8) | i1;
    const int myg2  = myg1 + 1;           // i1+1 <= 75 (pair never wraps a row)
    const float fj  = (float)j;

    const float* __restrict__ ob = out + (size_t)b * NCH * NCELL + cell1;
    const float* __restrict__ db = dt  + (size_t)b * NCH * NCELL + cell1;

    // Predicted corners for both items; track wave y-band while we go.
    float ax1[NKP], ay1[NKP], px1[NKP], py1[NKP];
    float ax2[NKP], ay2[NKP], px2[NKP], py2[NKP];
    float ymn = 1e30f, ymx = -1e30f;
    #pragma unroll
    for (int k = 0; k < NKP; k++) {
        float2 vx = *(const float2*)(ob + (2 * k)     * NCELL);  // cell1 even: aligned
        float2 vy = *(const float2*)(ob + (2 * k + 1) * NCELL);
        float cx1 = vx.x, cx2 = vx.y, cy1 = vy.x, cy2 = vy.y;
        if (k == 0) { cx1 = sigmoidf_(cx1); cx2 = sigmoidf_(cx2);
                      cy1 = sigmoidf_(cy1); cy2 = sigmoidf_(cy2); }
        ax1[k] = cx1; ax2[k] = cx2; ay1[k] = cy1; ay2[k] = cy2;
        px1[k] = (cx1 + (float)i1) * SX;  px2[k] = (cx2 + (float)(i1 + 1)) * SX;
        py1[k] = (cy1 + fj) * SY;         py2[k] = (cy2 + fj) * SY;
        ymn = fminf(ymn, fminf(py1[k], py2[k]));
        ymx = fmaxf(ymx, fmaxf(py1[k], py2[k]));
    }
    const float2 vcf  = *(const float2*)(ob + 18 * NCELL);
    const float2 vtcf = *(const float2*)(db + 18 * NCELL);
    const float conf1 = sigmoidf_(vcf.x),  conf2 = sigmoidf_(vcf.y);
    const float tcf1  = sigmoidf_(vtcf.x), tcf2  = sigmoidf_(vtcf.y);

    // Wave-wide exact y-band (butterfly min/max), then +/-80px gate margin.
    #pragma unroll
    for (int off = 32; off > 0; off >>= 1) {
        ymn = fminf(ymn, __shfl_xor(ymn, off, 64));
        ymx = fmaxf(ymx, __shfl_xor(ymx, off, 64));
    }
    const float ylo = ymn - 80.0f, yhi = ymx + 80.0f;

    float cur1 = 0.0f, cur2 = 0.0f;       // 9*cur; compare vs 9*SIL = 5.4
    int flag1 = 0, flag2 = 0, tc1 = 0, tc2 = 0;
    for (int t = 0; t < nv; t++) {
        const int g = s_gij[bi][t];
        if (g == myg1) { flag1 = 1; tc1 = s_cls[bi][t]; }   // last valid t wins
        if (g == myg2) { flag2 = 1; tc2 = s_cls[bi][t]; }
        float s1 = 0.0f, s2 = 0.0f;
        #pragma unroll
        for (int k = 0; k < NKP; k++) {
            const float2 gp = s_g[bi][t][k];
            // Wave-uniform cull: if |dy|>=80 for every lane, conf is exactly 0.
            if (gp.y > ylo && gp.y < yhi) {
                const float dx1 = gp.x - px1[k], dy1 = gp.y - py1[k];
                const float dx2 = gp.x - px2[k], dy2 = gp.y - py2[k];
                const float d21 = __builtin_fmaf(dx1, dx1, dy1 * dy1);
                const float d22 = __builtin_fmaf(dx2, dx2, dy2 * dy2);
                if (__any(fminf(d21, d22) < 6400.0f)) {
                    const float c1 = (__builtin_amdgcn_exp2f(
                        __builtin_fmaf(__builtin_amdgcn_sqrtf(d21), -C1, C0)) - 1.0f) * INV_EM1;
                    const float c2 = (__builtin_amdgcn_exp2f(
                        __builtin_fmaf(__builtin_amdgcn_sqrtf(d22), -C1, C0)) - 1.0f) * INV_EM1;
                    s1 += (d21 < 6400.0f) ? c1 : 0.0f;
                    s2 += (d22 < 6400.0f) ? c2 : 0.0f;
                }
            }
        }
        cur1 = fmaxf(cur1, s1);
        cur2 = fmaxf(cur2, s2);
    }

    float total;
    {
        const float cm1 = flag1 ? 5.0f : (cur1 > 5.4f ? 0.0f : 1.0f);
        const float cm2 = flag2 ? 5.0f : (cur2 > 5.4f ? 0.0f : 1.0f);
        const float d1 = conf1 - tcf1, d2 = conf2 - tcf2;
        total = 0.5f * (d1 * d1 * cm1 + d2 * d2 * cm2);
    }

    // Rare path (~20 of 5776 cells per batch): coord + cls loss.
    #pragma unroll
    for (int it = 0; it < 2; it++) {
        const int   fl   = it ? flag2 : flag1;
        if (!fl) continue;
        const int   tcls = it ? tc2 : tc1;
        const float* obi = ob + it;
        const float* dbi = db + it;
        const float* axi = it ? ax2 : ax1;
        const float* ayi = it ? ay2 : ay1;

        float cl = 0.0f;
        #pragma unroll
        for (int k = 0; k < NKP; k++) {
            float bx = dbi[(2 * k)     * NCELL];
            float by = dbi[(2 * k + 1) * NCELL];
            if (k == 0) { bx = sigmoidf_(bx); by = sigmoidf_(by); }
            const float e1 = axi[k] - bx;
            const float e2 = ayi[k] - by;
            cl += e1 * e1 + e2 * e2;
        }
        total += 0.5f * cl;

        // log-softmax CE; compile-time indices only (runtime index -> scratch).
        float cvv[NCLS];
        float mx = -1e30f, vt = 0.0f;
        #pragma unroll
        for (int c2 = 0; c2 < NCLS; c2++) {
            const float v = obi[(19 + c2) * NCELL];
            cvv[c2] = v;
            mx = fmaxf(mx, v);
            vt = (c2 == tcls) ? v : vt;
        }
        float se = 0.0f;
        #pragma unroll
        for (int c2 = 0; c2 < NCLS; c2++) se += __expf(cvv[c2] - mx);
        total += mx + __logf(se) - vt;
    }

    // Wave butterfly -> cross-wave LDS -> ONE plain store per block (no atomics)
    #pragma unroll
    for (int off = 32; off > 0; off >>= 1)
        total += __shfl_down(total, off, 64);
    if ((tid & 63) == 0) swsum[tid >> 6] = total;
    __syncthreads();
    if (tid == 0) {
        float sm = swsum[0];
        #pragma unroll
        for (int w = 1; w < BLOCK / 64; w++) sm += swsum[w];
        if (use_ws) partials[blockIdx.x] = sm;   // overwrites 0xAA poison
        else        atomicAdd(outp, sm);         // fallback (poison -3e-13, ok)
    }
}

__global__ __launch_bounds__(256) void reduce_partials(
    const float* __restrict__ p, float* __restrict__ outp)
{
    __shared__ float w[4];
    float s = 0.0f;
    for (int k = threadIdx.x; k < GRID; k += 256) s += p[k];
    #pragma unroll
    for (int off = 32; off > 0; off >>= 1)
        s += __shfl_down(s, off, 64);
    if ((threadIdx.x & 63) == 0) w[threadIdx.x >> 6] = s;
    __syncthreads();
    if (threadIdx.x == 0) outp[0] = w[0] + w[1] + w[2] + w[3];  // exact overwrite
}

extern "C" void kernel_launch(void* const* d_in, const int* in_sizes, int n_in,
                              void* d_out, int out_size, void* d_ws, size_t ws_size,
                              hipStream_t stream) {
    const float* out_p = (const float*)d_in[0];   // output
    const float* dt_p  = (const float*)d_in[1];   // distiled_target
    const float* tgt_p = (const float*)d_in[2];   // target
    const int use_ws = (d_ws != nullptr && ws_size >= GRID * sizeof(float));
    float* partials = (float*)d_ws;

    loss_main<<<GRID, BLOCK, 0, stream>>>(out_p, dt_p, tgt_p, (float*)d_out,
                                          partials, use_ws);
    if (use_ws)
        reduce_partials<<<1, 256, 0, stream>>>(partials, (float*)d_out);
}

// Round 3
// 83.991 us; speedup vs baseline: 1.1121x; 1.1121x over previous
//
#include <hip/hip_runtime.h>
#include <math.h>

// Problem constants (from reference)
#define NB    16
#define NH    76
#define NW    76
#define NCELL (NH * NW)      // 5776
#define NITEM (NB * NCELL)   // 92416
#define NCH   32             // 19 + NC
#define NKP   9
#define NCLS  13
#define NT    50
#define NLROW 21             // 2*NK + 3
#define BLOCK 128
#define GRID  (NITEM / BLOCK)  // 722 -- exact cover, 1 item/thread, no guard needed

// 1/(exp(2)-1)
#define INV_EM1 0.15651764274966565f
#define SX 8.421052631578947f    // 640/76
#define SY 6.315789473684211f    // 480/76
// exp(2 - d*0.025) == exp2(C0 - d*C1)  (fold log2e into the fma -> v_exp direct)
#define C0 2.885390081777927f    // 2*log2(e)
#define C1 0.036067376022224085f // 0.025*log2(e)

__device__ __forceinline__ float sigmoidf_(float x) {
    return 1.0f / (1.0f + __expf(-x));
}

// R6 = revert to R5's predecessor (the 83.6us kernel) + exp2-const-fold only.
// Post-mortem of the pairing experiment (93.4us, regression): 2 cells/thread
// dropped the grid to 722 waves on 1024 SIMDs (~0.7 waves/SIMD) while doubling
// each wave's dependent-latency chain -- this kernel is latency-bound, so
// sub-1 occupancy with 2x per-wave work ~doubles makespan. It also doubled the
// wave's spatial footprint (256-cell span), widening the y-band and nearly
// doubling the __any pass rate, which gutted the cull that justified pairing.
// Structure here (measured 83.6us):
//  - 1 cell/thread, BLOCK=128 x GRID=722 exact cover (1444 waves, ~1.4/SIMD)
//  - target rows staged once/block into LDS, pre-scaled to pixels; fixed trip
//    count via ballot-computed nvalid -> zero VMEM + no dependent break in t-loop
//  - wave-uniform __any(d^2 < 80^2) gate skips sqrt+exp on ~70% of corner evals
//  - native v_sqrt_f32 + v_exp_f32 (tolerance ~202 absolute; absmax was 0.0)
//  - per-block partial -> plain store to d_ws (overwrites poison), 1-block
//    reduce kernel writes d_out[0] exactly; zero same-address atomics
__global__ __launch_bounds__(BLOCK) void loss_main(
    const float* __restrict__ out,   // (NB, 32, 76, 76)
    const float* __restrict__ dt,    // (NB, 32, 76, 76)
    const float* __restrict__ tgt,   // (NB, 1050)
    float* __restrict__ outp,        // scalar loss (fallback path only)
    float* __restrict__ partials,    // d_ws: one slot per block
    int use_ws)
{
    // A block spans <=2 batch values (b-boundary every 5776 cells); stage both.
    __shared__ float2 s_g[2][NT][NKP];   // gt corners pre-scaled to pixels
    __shared__ int    s_gij[2][NT];      // (gj<<8)|gi
    __shared__ int    s_cls[2][NT];
    __shared__ int    s_nv[2];           // cumprod-validity count
    __shared__ float  swsum[BLOCK / 64];

    const int tid  = threadIdx.x;
    const int idx0 = blockIdx.x * BLOCK;
    const int b0   = idx0 / NCELL;
    const int b1   = (idx0 + BLOCK - 1) / NCELL;   // b0 or b0+1

    // Stage 100 rows (2 b-values x 50 t), one row per thread.
    for (int u = tid; u < 2 * NT; u += BLOCK) {
        const int bsel = u / NT;
        const int t    = u - bsel * NT;
        const int bb   = bsel ? b1 : b0;
        const float* __restrict__ r = tgt + (size_t)bb * (NT * NLROW) + t * NLROW;
        #pragma unroll
        for (int k = 0; k < NKP; k++)
            s_g[bsel][t][k] = make_float2(r[1 + 2 * k] * 640.0f, r[2 + 2 * k] * 480.0f);
        const int gi = (int)(r[1] * (float)NW);
        const int gj = (int)(r[2] * (float)NH);
        s_gij[bsel][t] = (gj << 8) | gi;
        s_cls[bsel][t] = min(max((int)r[0], 0), NCLS - 1);
    }
    // nvalid per b via ballot: wave w handles bsel=w (BLOCK=128 -> exactly 2 waves).
    {
        const int wv = tid >> 6, ln = tid & 63;
        const int bb = wv ? b1 : b0;
        const float x0 = (ln < NT) ? tgt[(size_t)bb * (NT * NLROW) + ln * NLROW + 1] : 0.0f;
        const unsigned long long zmask = __ballot(x0 == 0.0f);  // lanes>=NT forced set
        if (ln == 0) s_nv[wv] = (int)__ffsll(zmask) - 1;
    }
    __syncthreads();

    const int idx  = idx0 + tid;          // always < NITEM (exact grid)
    const int b    = idx / NCELL;
    const int cell = idx - b * NCELL;
    const int j    = cell / NW;
    const int i    = cell - j * NW;
    const int bi   = (b != b0);
    const int myg  = (j << 8) | i;
    const int nv   = s_nv[bi];
    const float fi = (float)i, fj = (float)j;

    const float* __restrict__ ob = out + (size_t)b * NCH * NCELL + cell;
    const float* __restrict__ db = dt  + (size_t)b * NCH * NCELL + cell;

    // Predicted corners: raw transformed channel values (ax/ay) for the coord
    // loss, pixel-space positions (px/py) for the conf search.
    float ax[NKP], ay[NKP], px[NKP], py[NKP];
    #pragma unroll
    for (int k = 0; k < NKP; k++) {
        float cx = ob[(2 * k)     * NCELL];
        float cy = ob[(2 * k + 1) * NCELL];
        if (k == 0) { cx = sigmoidf_(cx); cy = sigmoidf_(cy); }
        ax[k] = cx; ay[k] = cy;
        px[k] = (cx + fi) * SX;
        py[k] = (cy + fj) * SY;
    }
    const float conf  = sigmoidf_(ob[18 * NCELL]);
    const float tconf = sigmoidf_(db[18 * NCELL]);

    float cur9 = 0.0f;                    // 9 * cur; compare vs 9*SIL = 5.4
    int flag = 0, tcls = 0;
    for (int t = 0; t < nv; t++) {
        const int g = s_gij[bi][t];
        if (g == myg) { flag = 1; tcls = s_cls[bi][t]; }   // last valid t wins
        float s = 0.0f;
        #pragma unroll
        for (int k = 0; k < NKP; k++) {
            const float2 gp = s_g[bi][t][k];
            const float dx = gp.x - px[k];
            const float dy = gp.y - py[k];
            const float d2 = __builtin_fmaf(dx, dx, dy * dy);
            // Wave-uniform reject: sqrt+exp only if some lane is inside 80px.
            if (__any(d2 < 6400.0f)) {
                const float c = (__builtin_amdgcn_exp2f(
                    __builtin_fmaf(__builtin_amdgcn_sqrtf(d2), -C1, C0)) - 1.0f) * INV_EM1;
                s += (d2 < 6400.0f) ? c : 0.0f;
            }
        }
        cur9 = fmaxf(cur9, s);
    }

    float total;
    {
        const float cmask = flag ? 5.0f : (cur9 > 5.4f ? 0.0f : 1.0f);
        const float dcf = conf - tconf;
        total = 0.5f * dcf * dcf * cmask;
    }

    if (flag) {   // rare (<=20 cells of 5776 per batch)
        float cl = 0.0f;
        #pragma unroll
        for (int k = 0; k < NKP; k++) {
            float bx = db[(2 * k)     * NCELL];
            float by = db[(2 * k + 1) * NCELL];
            if (k == 0) { bx = sigmoidf_(bx); by = sigmoidf_(by); }
            const float d1 = ax[k] - bx;
            const float d2_ = ay[k] - by;
            cl += d1 * d1 + d2_ * d2_;
        }
        total += 0.5f * cl;

        // log-softmax CE; compile-time indices only (runtime index -> scratch,
        // rule #20), cv[tcls] tracked via select.
        float cvv[NCLS];
        float mx = -1e30f, vt = 0.0f;
        #pragma unroll
        for (int c2 = 0; c2 < NCLS; c2++) {
            const float v = ob[(19 + c2) * NCELL];
            cvv[c2] = v;
            mx = fmaxf(mx, v);
            vt = (c2 == tcls) ? v : vt;
        }
        float se = 0.0f;
        #pragma unroll
        for (int c2 = 0; c2 < NCLS; c2++) se += __expf(cvv[c2] - mx);
        total += mx + __logf(se) - vt;
    }

    // Wave butterfly -> cross-wave LDS -> ONE plain store per block (no atomics)
    #pragma unroll
    for (int off = 32; off > 0; off >>= 1)
        total += __shfl_down(total, off, 64);
    if ((tid & 63) == 0) swsum[tid >> 6] = total;
    __syncthreads();
    if (tid == 0) {
        float sm = swsum[0];
        #pragma unroll
        for (int w = 1; w < BLOCK / 64; w++) sm += swsum[w];
        if (use_ws) partials[blockIdx.x] = sm;   // overwrites 0xAA poison
        else        atomicAdd(outp, sm);         // fallback (poison -3e-13, ok)
    }
}

__global__ __launch_bounds__(256) void reduce_partials(
    const float* __restrict__ p, float* __restrict__ outp)
{
    __shared__ float w[4];
    float s = 0.0f;
    for (int k = threadIdx.x; k < GRID; k += 256) s += p[k];
    #pragma unroll
    for (int off = 32; off > 0; off >>= 1)
        s += __shfl_down(s, off, 64);
    if ((threadIdx.x & 63) == 0) w[threadIdx.x >> 6] = s;
    __syncthreads();
    if (threadIdx.x == 0) outp[0] = w[0] + w[1] + w[2] + w[3];  // exact overwrite
}

extern "C" void kernel_launch(void* const* d_in, const int* in_sizes, int n_in,
                              void* d_out, int out_size, void* d_ws, size_t ws_size,
                              hipStream_t stream) {
    const float* out_p = (const float*)d_in[0];   // output
    const float* dt_p  = (const float*)d_in[1];   // distiled_target
    const float* tgt_p = (const float*)d_in[2];   // target
    const int use_ws = (d_ws != nullptr && ws_size >= GRID * sizeof(float));
    float* partials = (float*)d_ws;

    loss_main<<<GRID, BLOCK, 0, stream>>>(out_p, dt_p, tgt_p, (float*)d_out,
                                          partials, use_ws);
    if (use_ws)
        reduce_partials<<<1, 256, 0, stream>>>(partials, (float*)d_out);
}